// Round 9
// baseline (325.926 us; speedup 1.0000x reference)
//
#include <hip/hip_runtime.h>
#include <hip/hip_bf16.h>
#include <math.h>

// Problem constants
#define S_LEN 4096
#define D_MODEL 1024
#define C_CONV 3072
#define H_HEADS 32
#define HEAD_D 32
#define V_D 32
#define K_CONV 4
#define CHUNK 64
#define NCH (S_LEN / CHUNK)                 // 64
#define SC_STRIDE (HEAD_D * V_D + HEAD_D)   // 1056 floats per (chunk, head)

typedef __attribute__((ext_vector_type(8))) short short8;
typedef __attribute__((ext_vector_type(4))) float f32x4;

// compile-time float4 component access (folds under #pragma unroll)
#define F4C(v, k) ((k) == 0 ? (v).x : (k) == 1 ? (v).y : (k) == 2 ? (v).z : (v).w)

// ---------------------------------------------------------------------------
// helpers
// ---------------------------------------------------------------------------
__device__ __forceinline__ ushort f32_to_bf16_rne(float f) {
  unsigned u = __float_as_uint(f);
  unsigned rounding = 0x7FFFu + ((u >> 16) & 1u);
  return (ushort)((u + rounding) >> 16);
}

__device__ __forceinline__ void gload_lds16(const void* g, void* l) {
  __builtin_amdgcn_global_load_lds(
      (const __attribute__((address_space(1))) void*)g,
      (__attribute__((address_space(3))) void*)l, 16, 0, 0);
}

// ---------------------------------------------------------------------------
// fp32 -> (bf16 hi, bf16 lo) split.  lo = bf16(x - fp32(hi)).
// ---------------------------------------------------------------------------
__global__ __launch_bounds__(256) void split_bf16(
    const float* __restrict__ in, ushort* __restrict__ hi,
    ushort* __restrict__ lo, int n4) {
  int i = blockIdx.x * 256 + threadIdx.x;
  const int stride = gridDim.x * 256;
  for (; i < n4; i += stride) {
    const float4 v = reinterpret_cast<const float4*>(in)[i];
    float arr[4] = {v.x, v.y, v.z, v.w};
    ushort hh[4], ll[4];
#pragma unroll
    for (int j = 0; j < 4; ++j) {
      const ushort hb = f32_to_bf16_rne(arr[j]);
      const float hf = __uint_as_float((unsigned)hb << 16);
      hh[j] = hb;
      ll[j] = f32_to_bf16_rne(arr[j] - hf);
    }
    ushort4 h = {hh[0], hh[1], hh[2], hh[3]};
    ushort4 lw = {ll[0], ll[1], ll[2], ll[3]};
    reinterpret_cast<ushort4*>(hi)[i] = h;
    reinterpret_cast<ushort4*>(lo)[i] = lw;
  }
}

// ---------------------------------------------------------------------------
// bf16-split-3 NT GEMM, BK=32, 32KB(NF=4)/24KB(NF=2) LDS -> 4-5 blocks/CU.
//   C[m][n] = sum_k A[m][k]*B[n][k] + bias[n]   (fp32 MFMA acc)
// 128 x (NF*32) tile, 4 waves (2x2), wave tile 64 x (NF*16).
// Swizzle (rule 21, 4 slots/row): store slot sp holds logical sg=sp^((row>>1)&3);
// read logical g at physical g^((row>>1)&3). Same involution both sides.
// ---------------------------------------------------------------------------
#define GBM 128
#define GBK 32

template <int NF>   // B-fragments per wave; BN = NF*32
__global__ __launch_bounds__(256, 4) void gemm_nt_split3(
    const ushort* __restrict__ Ah, const ushort* __restrict__ Al,
    const ushort* __restrict__ Bh, const ushort* __restrict__ Bl,
    const float* __restrict__ bias, float* __restrict__ C,
    int M, int N, int K) {
  constexpr int BN = NF * 32;
  __shared__ ushort lds[8192 + 2 * BN * 32];
  ushort* sAh = lds;                    // 128x32
  ushort* sAl = lds + 4096;             // 128x32
  ushort* sBh = lds + 8192;             // BNx32
  ushort* sBl = lds + 8192 + BN * 32;   // BNx32

  const int t = threadIdx.x;
  const int l = t & 63;
  const int w = t >> 6;          // wave 0..3
  const int wr = w >> 1;         // wave row (0..1)
  const int wc = w & 1;          // wave col (0..1)
  const int bm = blockIdx.y * GBM;
  const int bn = blockIdx.x * BN;
  const int r16 = l & 15;
  const int g = l >> 4;          // k-slot 0..3 (k = g*8)

  f32x4 acc[4][NF];
#pragma unroll
  for (int m = 0; m < 4; ++m)
#pragma unroll
    for (int n = 0; n < NF; ++n) acc[m][n] = {0.f, 0.f, 0.f, 0.f};

  // stage R-row x 32-col bf16 tile: linear LDS dest (unit u -> u*16B,
  // wave-uniform base + lane*16), source pre-swizzled.
  auto stage = [&](const ushort* __restrict__ G, ushort* Lt, int base_row,
                   int k0, int nu /* = R*4 units */) {
    for (int u0 = 0; u0 < nu; u0 += 256) {
      const int u = u0 + t;
      const int row = u >> 2;
      const int sp = u & 3;
      const int sg = sp ^ ((row >> 1) & 3);
      gload_lds16(&G[(size_t)(base_row + row) * K + k0 + sg * 8], &Lt[u * 8]);
    }
  };

  for (int k0 = 0; k0 < K; k0 += GBK) {
    stage(Ah, sAh, bm, k0, 512);
    stage(Al, sAl, bm, k0, 512);
    stage(Bh, sBh, bn, k0, BN * 4);
    stage(Bl, sBl, bn, k0, BN * 4);
    __syncthreads();   // drains vmcnt before any LDS read

    short8 afh[4], afl[4], bfh[NF], bfl[NF];
#pragma unroll
    for (int m = 0; m < 4; ++m) {
      const int arow = wr * 64 + m * 16 + r16;
      const int off = arow * 64 + (((g ^ ((arow >> 1) & 3))) << 4);
      afh[m] = *reinterpret_cast<const short8*>((const char*)sAh + off);
      afl[m] = *reinterpret_cast<const short8*>((const char*)sAl + off);
    }
#pragma unroll
    for (int n = 0; n < NF; ++n) {
      const int brow = wc * (NF * 16) + n * 16 + r16;
      const int off = brow * 64 + (((g ^ ((brow >> 1) & 3))) << 4);
      bfh[n] = *reinterpret_cast<const short8*>((const char*)sBh + off);
      bfl[n] = *reinterpret_cast<const short8*>((const char*)sBl + off);
    }
#pragma unroll
    for (int m = 0; m < 4; ++m)
#pragma unroll
      for (int n = 0; n < NF; ++n) {
        acc[m][n] = __builtin_amdgcn_mfma_f32_16x16x32_bf16(
            afh[m], bfh[n], acc[m][n], 0, 0, 0);
        acc[m][n] = __builtin_amdgcn_mfma_f32_16x16x32_bf16(
            afh[m], bfl[n], acc[m][n], 0, 0, 0);
        acc[m][n] = __builtin_amdgcn_mfma_f32_16x16x32_bf16(
            afl[m], bfh[n], acc[m][n], 0, 0, 0);
      }
    __syncthreads();   // LDS reuse next iteration
  }

  // epilogue: C/D layout col = lane&15, row = (lane>>4)*4 + reg  (m89-verified)
#pragma unroll
  for (int n = 0; n < NF; ++n) {
    const int col = bn + wc * (NF * 16) + n * 16 + r16;
    const float bb = bias[col];
#pragma unroll
    for (int m = 0; m < 4; ++m) {
      const int row0 = bm + wr * 64 + m * 16 + g * 4;
#pragma unroll
      for (int j = 0; j < 4; ++j)
        C[(size_t)(row0 + j) * N + col] = acc[m][n][j] + bb;
    }
  }
}

// ---------------------------------------------------------------------------
// Depthwise causal conv (K=4) + conv bias + SiLU; then elu+1 for q/k channels.
// ---------------------------------------------------------------------------
__global__ __launch_bounds__(256) void conv_silu_act(
    const float* __restrict__ qkv, const float* __restrict__ conv_w,
    const float* __restrict__ conv_b, float* __restrict__ act) {
  const int gid = blockIdx.x * 256 + threadIdx.x;
  const int nc4 = C_CONV / 4;
  if (gid >= S_LEN * nc4) return;
  const int s = gid / nc4;
  const int c = (gid % nc4) * 4;

  float w[4][4];
#pragma unroll
  for (int cc = 0; cc < 4; ++cc) {
    const float4 wv = *reinterpret_cast<const float4*>(&conv_w[(c + cc) * 4]);
    w[cc][0] = wv.x; w[cc][1] = wv.y; w[cc][2] = wv.z; w[cc][3] = wv.w;
  }
  const float4 bv = *reinterpret_cast<const float4*>(&conv_b[c]);
  float z[4] = {bv.x, bv.y, bv.z, bv.w};

#pragma unroll
  for (int j = 0; j < 4; ++j) {
    const int sp = s - 3 + j;
    if (sp >= 0) {
      const float4 in = *reinterpret_cast<const float4*>(
          &qkv[(size_t)sp * C_CONV + c]);
      z[0] += in.x * w[0][j]; z[1] += in.y * w[1][j];
      z[2] += in.z * w[2][j]; z[3] += in.w * w[3][j];
    }
  }

  float out[4];
  const bool is_qk = (c < 2 * D_MODEL);
#pragma unroll
  for (int cc = 0; cc < 4; ++cc) {
    float a = z[cc] / (1.0f + expf(-z[cc]));           // silu
    if (is_qk) a = (a > 0.0f) ? (a + 1.0f) : expf(a);  // elu(a)+1
    out[cc] = a;
  }
  float4 ov = {out[0], out[1], out[2], out[3]};
  *reinterpret_cast<float4*>(&act[(size_t)s * C_CONV + c]) = ov;
}

// ---------------------------------------------------------------------------
// Pass 1: per-chunk KV outer-product sums and K sums. (register-tiled)
// ---------------------------------------------------------------------------
__global__ __launch_bounds__(256) void chunk_sums(
    const float* __restrict__ act, float* __restrict__ SC) {
  const int ch = blockIdx.x;
  const int h = blockIdx.y;
  const int t = threadIdx.x;
  __shared__ float ks[CHUNK][32];
  __shared__ float vs[CHUNK][36];   // padded for conflict-free float4 reads

#pragma unroll
  for (int i = 0; i < 2; ++i) {
    int idx = t + 256 * i;
    int r = idx >> 3;
    int c0 = (idx & 7) * 4;
    const size_t row = (size_t)(ch * CHUNK + r) * C_CONV;
    const float4 kv4 = *reinterpret_cast<const float4*>(
        &act[row + D_MODEL + h * 32 + c0]);
    *reinterpret_cast<float4*>(&ks[r][c0]) = kv4;
    const float4 vv4 = *reinterpret_cast<const float4*>(
        &act[row + 2 * D_MODEL + h * 32 + c0]);
    *reinterpret_cast<float4*>(&vs[r][c0]) = vv4;
  }
  __syncthreads();

  const int d = t >> 3;             // 0..31
  const int c4 = (t & 7) * 4;       // 0,4,...,28
  float4 acc = {0.f, 0.f, 0.f, 0.f};
  float ksum = 0.f;
#pragma unroll 4
  for (int s = 0; s < CHUNK; ++s) {
    const float kv = ks[s][d];
    const float4 vv = *reinterpret_cast<const float4*>(&vs[s][c4]);
    acc.x += kv * vv.x; acc.y += kv * vv.y;
    acc.z += kv * vv.z; acc.w += kv * vv.w;
    ksum += kv;
  }
  float* out = &SC[(size_t)(ch * H_HEADS + h) * SC_STRIDE];
  *reinterpret_cast<float4*>(&out[d * 32 + c4]) = acc;
  if ((t & 7) == 0) out[1024 + d] = ksum;
}

// ---------------------------------------------------------------------------
// Pass 2: exclusive prefix over chunks (per head).
// ---------------------------------------------------------------------------
__global__ __launch_bounds__(256) void chunk_prefix(
    const float* __restrict__ SC, float* __restrict__ SP) {
  const int h = blockIdx.x;
  const int t = threadIdx.x;
  for (int e = t; e < SC_STRIDE; e += 256) {
    float run = 0.f;
    for (int c = 0; c < NCH; ++c) {
      const size_t off = (size_t)(c * H_HEADS + h) * SC_STRIDE + e;
      SP[off] = run;
      run += SC[off];
    }
  }
}

// ---------------------------------------------------------------------------
// Pass 3: intra-chunk causal attention + inter-chunk state. (register-tiled)
// Writes ctx directly as bf16 hi/lo splits (fused epilogue for GEMM2).
// ---------------------------------------------------------------------------
__global__ __launch_bounds__(256) void chunk_ctx(
    const float* __restrict__ act, const float* __restrict__ SP,
    ushort* __restrict__ ctx_h, ushort* __restrict__ ctx_l) {
  const int ch = blockIdx.x;
  const int h = blockIdx.y;
  const int t = threadIdx.x;

  __shared__ float qs[CHUNK][36];     // Q rows, float4-readable, 2-way banks
  __shared__ float ksT[32][68];       // K transposed: ksT[d][s']
  __shared__ float vs[CHUNK][36];     // V rows, float4-readable
  __shared__ float KVp[32][36];       // KVprev[d][t], float4-readable
  __shared__ float Amat[CHUNK][68];   // masked scores
  __shared__ float Kp[32];
  __shared__ float denomp[CHUNK][4];
  __shared__ float denom[CHUNK];

  // ---- staging: coalesced global float4 loads
#pragma unroll
  for (int i = 0; i < 2; ++i) {
    const int idx = t + 256 * i;      // 0..511
    const int r = idx >> 3;
    const int c0 = (idx & 7) * 4;
    const size_t row = (size_t)(ch * CHUNK + r) * C_CONV;
    float4 v4;
    v4 = *reinterpret_cast<const float4*>(&act[row + h * 32 + c0]);
    *reinterpret_cast<float4*>(&qs[r][c0]) = v4;
    v4 = *reinterpret_cast<const float4*>(&act[row + D_MODEL + h * 32 + c0]);
    ksT[c0 + 0][r] = v4.x; ksT[c0 + 1][r] = v4.y;
    ksT[c0 + 2][r] = v4.z; ksT[c0 + 3][r] = v4.w;
    v4 = *reinterpret_cast<const float4*>(&act[row + 2 * D_MODEL + h * 32 + c0]);
    *reinterpret_cast<float4*>(&vs[r][c0]) = v4;
  }
  const float* sp = &SP[(size_t)(ch * H_HEADS + h) * SC_STRIDE];
  {
    const float4 v4 = *reinterpret_cast<const float4*>(&sp[t * 4]);
    *reinterpret_cast<float4*>(&KVp[t >> 3][(t & 7) * 4]) = v4;
  }
  if (t < 32) Kp[t] = sp[1024 + t];
  __syncthreads();

  // ---- step1: Amat = tril(Q K^T), 4x4 register tile per thread
  {
    const int tm = t >> 4;            // row group 0..15
    const int tn = t & 15;            // col group 0..15
    float a1[4][4] = {{0.f}};
#pragma unroll
    for (int g = 0; g < 8; ++g) {
      const int d0 = g * 4;
      float4 qv[4], kq[4];
#pragma unroll
      for (int i = 0; i < 4; ++i)
        qv[i] = *reinterpret_cast<const float4*>(&qs[tm * 4 + i][d0]);
#pragma unroll
      for (int dd = 0; dd < 4; ++dd)
        kq[dd] = *reinterpret_cast<const float4*>(&ksT[d0 + dd][tn * 4]);
#pragma unroll
      for (int i = 0; i < 4; ++i)
#pragma unroll
        for (int dd = 0; dd < 4; ++dd) {
          const float qa = F4C(qv[i], dd);
          a1[i][0] += qa * kq[dd].x;
          a1[i][1] += qa * kq[dd].y;
          a1[i][2] += qa * kq[dd].z;
          a1[i][3] += qa * kq[dd].w;
        }
    }
#pragma unroll
    for (int i = 0; i < 4; ++i) {
      const int s = tm * 4 + i;
      float4 o;
      o.x = (tn * 4 + 0 <= s) ? a1[i][0] : 0.f;
      o.y = (tn * 4 + 1 <= s) ? a1[i][1] : 0.f;
      o.z = (tn * 4 + 2 <= s) ? a1[i][2] : 0.f;
      o.w = (tn * 4 + 3 <= s) ? a1[i][3] : 0.f;
      *reinterpret_cast<float4*>(&Amat[s][tn * 4]) = o;
    }
  }
  __syncthreads();

  // ---- step2: denom, split across the 4 waves
  {
    const int row = t & 63;
    const int qd = t >> 6;            // 0..3
    float part = 0.f;
#pragma unroll
    for (int j = 0; j < 16; ++j) part += Amat[row][qd * 16 + j];
    if (qd < 2) {
#pragma unroll
      for (int j = 0; j < 16; ++j)
        part += qs[row][qd * 16 + j] * Kp[qd * 16 + j];
    }
    denomp[row][qd] = part;
  }
  __syncthreads();
  if (t < CHUNK) {
    const float4 dp = *reinterpret_cast<const float4*>(&denomp[t][0]);
    denom[t] = dp.x + dp.y + dp.z + dp.w;
  }
  __syncthreads();

  // ---- step3: ctx = (A·V + Q·KVp)/denom, 2 rows x 4 cols per thread
  {
    const int r2 = t >> 3;            // 0..31 -> rows 2*r2, 2*r2+1
    const int c4 = (t & 7) * 4;       // col group
    float a3[2][4] = {{0.f}};
#pragma unroll
    for (int sg = 0; sg < 16; ++sg) {
      const int s0 = sg * 4;
      float4 av[2];
      av[0] = *reinterpret_cast<const float4*>(&Amat[r2 * 2 + 0][s0]);
      av[1] = *reinterpret_cast<const float4*>(&Amat[r2 * 2 + 1][s0]);
      float4 vv[4];
#pragma unroll
      for (int ss = 0; ss < 4; ++ss)
        vv[ss] = *reinterpret_cast<const float4*>(&vs[s0 + ss][c4]);
#pragma unroll
      for (int i = 0; i < 2; ++i)
#pragma unroll
        for (int ss = 0; ss < 4; ++ss) {
          const float aa = F4C(av[i], ss);
          a3[i][0] += aa * vv[ss].x;
          a3[i][1] += aa * vv[ss].y;
          a3[i][2] += aa * vv[ss].z;
          a3[i][3] += aa * vv[ss].w;
        }
    }
#pragma unroll
    for (int g = 0; g < 8; ++g) {
      const int d0 = g * 4;
      float4 qv[2];
      qv[0] = *reinterpret_cast<const float4*>(&qs[r2 * 2 + 0][d0]);
      qv[1] = *reinterpret_cast<const float4*>(&qs[r2 * 2 + 1][d0]);
      float4 kv[4];
#pragma unroll
      for (int dd = 0; dd < 4; ++dd)
        kv[dd] = *reinterpret_cast<const float4*>(&KVp[d0 + dd][c4]);
#pragma unroll
      for (int i = 0; i < 2; ++i)
#pragma unroll
        for (int dd = 0; dd < 4; ++dd) {
          const float qa = F4C(qv[i], dd);
          a3[i][0] += qa * kv[dd].x;
          a3[i][1] += qa * kv[dd].y;
          a3[i][2] += qa * kv[dd].z;
          a3[i][3] += qa * kv[dd].w;
        }
    }
    // epilogue: divide + fused bf16 hi/lo split, vectorized ushort4 stores
#pragma unroll
    for (int i = 0; i < 2; ++i) {
      const int srow = r2 * 2 + i;
      const float dn = denom[srow];
      const size_t off = (size_t)(ch * CHUNK + srow) * D_MODEL + h * 32 + c4;
      ushort4 hv, lv;
      ushort hh[4], ll[4];
#pragma unroll
      for (int c = 0; c < 4; ++c) {
        const float val = a3[i][c] / dn;
        const ushort hb = f32_to_bf16_rne(val);
        hh[c] = hb;
        ll[c] = f32_to_bf16_rne(val - __uint_as_float((unsigned)hb << 16));
      }
      hv.x = hh[0]; hv.y = hh[1]; hv.z = hh[2]; hv.w = hh[3];
      lv.x = ll[0]; lv.y = ll[1]; lv.z = ll[2]; lv.w = ll[3];
      *reinterpret_cast<ushort4*>(&ctx_h[off]) = hv;
      *reinterpret_cast<ushort4*>(&ctx_l[off]) = lv;
    }
  }
}

// ---------------------------------------------------------------------------
// Workspace layout (bytes), total 96 MB required (see round-4 comments).
// ---------------------------------------------------------------------------
extern "C" void kernel_launch(void* const* d_in, const int* in_sizes, int n_in,
                              void* d_out, int out_size, void* d_ws, size_t ws_size,
                              hipStream_t stream) {
  const float* x      = (const float*)d_in[0];
  const float* Wqkv_w = (const float*)d_in[1];
  const float* Wqkv_b = (const float*)d_in[2];
  const float* conv_w = (const float*)d_in[3];
  const float* conv_b = (const float*)d_in[4];
  const float* out_w  = (const float*)d_in[5];
  const float* out_b  = (const float*)d_in[6];
  float* out = (float*)d_out;

  char* ws = (char*)d_ws;
  float*  qkv_raw = (float*)(ws);
  float*  SC      = (float*)(ws);
  float*  SP      = (float*)(ws + 8650752);
  ushort* ch      = (ushort*)(ws + 17301504);
  ushort* cl      = (ushort*)(ws + 25690112);
  float*  act     = (float*)(ws + 50331648);
  ushort* xh      = (ushort*)(ws + 50331648);
  ushort* xl      = (ushort*)(ws + 58720256);
  ushort* wh      = (ushort*)(ws + 67108864);
  ushort* wl      = (ushort*)(ws + 73400320);
  ushort* oh      = (ushort*)(ws + 50331648);
  ushort* ol      = (ushort*)(ws + 52428800);

  // 0. split x and Wqkv_w into bf16 hi/lo
  split_bf16<<<2048, 256, 0, stream>>>(x, xh, xl, S_LEN * D_MODEL / 4);
  split_bf16<<<2048, 256, 0, stream>>>(Wqkv_w, wh, wl, C_CONV * D_MODEL / 4);

  // 1. QKV GEMM (bf16-split3 MFMA, BK=32): -> qkv_raw [4096][3072]
  {
    dim3 grid(C_CONV / 128, S_LEN / GBM);   // 24 x 32 = 768 blocks
    gemm_nt_split3<4><<<grid, 256, 0, stream>>>(xh, xl, wh, wl, Wqkv_b,
                                                qkv_raw, S_LEN, C_CONV,
                                                D_MODEL);
  }
  // 2. causal depthwise conv + SiLU + elu+1 -> act (overwrites xh..wl region)
  {
    int total = S_LEN * (C_CONV / 4);
    conv_silu_act<<<(total + 255) / 256, 256, 0, stream>>>(qkv_raw, conv_w,
                                                           conv_b, act);
  }
  // 3. chunk KV sums (overwrites qkv_raw region)
  {
    dim3 grid(NCH, H_HEADS);
    chunk_sums<<<grid, 256, 0, stream>>>(act, SC);
  }
  // 4. exclusive prefix over chunks
  chunk_prefix<<<H_HEADS, 256, 0, stream>>>(SC, SP);
  // 5. intra-chunk attention -> ctx bf16 hi/lo (fused split)
  {
    dim3 grid(NCH, H_HEADS);
    chunk_ctx<<<grid, 256, 0, stream>>>(act, SP, ch, cl);
  }
  // 6. split out_w (act now dead), then output GEMM (BN=64 -> 512 blocks)
  split_bf16<<<1024, 256, 0, stream>>>(out_w, oh, ol, D_MODEL * D_MODEL / 4);
  {
    dim3 grid(D_MODEL / 64, S_LEN / GBM);   // 16 x 32 = 512 blocks
    gemm_nt_split3<2><<<grid, 256, 0, stream>>>(ch, cl, oh, ol, out_b, out,
                                                S_LEN, D_MODEL, D_MODEL);
  }
}

// Round 10
// 321.347 us; speedup vs baseline: 1.0142x; 1.0142x over previous
//
#include <hip/hip_runtime.h>
#include <hip/hip_bf16.h>
#include <math.h>

// Problem constants
#define S_LEN 4096
#define D_MODEL 1024
#define C_CONV 3072
#define H_HEADS 32
#define HEAD_D 32
#define V_D 32
#define K_CONV 4
#define CHUNK 64
#define NCH (S_LEN / CHUNK)                 // 64
#define SC_STRIDE (HEAD_D * V_D + HEAD_D)   // 1056 floats per (chunk, head)

typedef __attribute__((ext_vector_type(8))) short short8;
typedef __attribute__((ext_vector_type(4))) float f32x4;

// compile-time float4 component access (folds under #pragma unroll)
#define F4C(v, k) ((k) == 0 ? (v).x : (k) == 1 ? (v).y : (k) == 2 ? (v).z : (v).w)

// ---------------------------------------------------------------------------
// helpers
// ---------------------------------------------------------------------------
__device__ __forceinline__ ushort f32_to_bf16_rne(float f) {
  unsigned u = __float_as_uint(f);
  unsigned rounding = 0x7FFFu + ((u >> 16) & 1u);
  return (ushort)((u + rounding) >> 16);
}

__device__ __forceinline__ void gload_lds16(const void* g, void* l) {
  __builtin_amdgcn_global_load_lds(
      (const __attribute__((address_space(1))) void*)g,
      (__attribute__((address_space(3))) void*)l, 16, 0, 0);
}

__device__ __forceinline__ void split_one4(const float* __restrict__ in,
                                           ushort* __restrict__ hi,
                                           ushort* __restrict__ lo, int i) {
  const float4 v = reinterpret_cast<const float4*>(in)[i];
  float arr[4] = {v.x, v.y, v.z, v.w};
  ushort hh[4], ll[4];
#pragma unroll
  for (int j = 0; j < 4; ++j) {
    const ushort hb = f32_to_bf16_rne(arr[j]);
    const float hf = __uint_as_float((unsigned)hb << 16);
    hh[j] = hb;
    ll[j] = f32_to_bf16_rne(arr[j] - hf);
  }
  ushort4 h = {hh[0], hh[1], hh[2], hh[3]};
  ushort4 lw = {ll[0], ll[1], ll[2], ll[3]};
  reinterpret_cast<ushort4*>(hi)[i] = h;
  reinterpret_cast<ushort4*>(lo)[i] = lw;
}

// fp32 -> (bf16 hi, bf16 lo) split, single tensor (grid-stride).
__global__ __launch_bounds__(256) void split_bf16(
    const float* __restrict__ in, ushort* __restrict__ hi,
    ushort* __restrict__ lo, int n4) {
  int i = blockIdx.x * 256 + threadIdx.x;
  const int stride = gridDim.x * 256;
  for (; i < n4; i += stride) split_one4(in, hi, lo, i);
}

// fused split of TWO tensors in one launch (grid covers n4a+n4b exactly).
__global__ __launch_bounds__(256) void split_bf16_x2(
    const float* __restrict__ a, ushort* __restrict__ ah,
    ushort* __restrict__ al, int n4a,
    const float* __restrict__ b, ushort* __restrict__ bh,
    ushort* __restrict__ bl, int n4b) {
  const int gid = blockIdx.x * 256 + threadIdx.x;
  if (gid < n4a) {
    split_one4(a, ah, al, gid);
  } else if (gid < n4a + n4b) {
    split_one4(b, bh, bl, gid - n4a);
  }
}

// ---------------------------------------------------------------------------
// bf16-split-3 NT GEMM, BK=32, 32KB LDS (NF=4) -> grid-limited occupancy.
//   C[m][n] = sum_k A[m][k]*B[n][k] + bias[n]   (fp32 MFMA acc)
// 128 x (NF*32) tile, 4 waves (2x2), wave tile 64 x (NF*16).
// Swizzle (rule 21, 4 slots/row): store slot sp holds logical sg=sp^((row>>1)&3);
// read logical g at physical g^((row>>1)&3). Same involution both sides.
// ---------------------------------------------------------------------------
#define GBM 128
#define GBK 32

template <int NF>   // B-fragments per wave; BN = NF*32
__global__ __launch_bounds__(256, 4) void gemm_nt_split3(
    const ushort* __restrict__ Ah, const ushort* __restrict__ Al,
    const ushort* __restrict__ Bh, const ushort* __restrict__ Bl,
    const float* __restrict__ bias, float* __restrict__ C,
    int M, int N, int K) {
  constexpr int BN = NF * 32;
  __shared__ ushort lds[8192 + 2 * BN * 32];
  ushort* sAh = lds;                    // 128x32
  ushort* sAl = lds + 4096;             // 128x32
  ushort* sBh = lds + 8192;             // BNx32
  ushort* sBl = lds + 8192 + BN * 32;   // BNx32

  const int t = threadIdx.x;
  const int l = t & 63;
  const int w = t >> 6;          // wave 0..3
  const int wr = w >> 1;         // wave row (0..1)
  const int wc = w & 1;          // wave col (0..1)
  const int bm = blockIdx.y * GBM;
  const int bn = blockIdx.x * BN;
  const int r16 = l & 15;
  const int g = l >> 4;          // k-slot 0..3 (k = g*8)

  f32x4 acc[4][NF];
#pragma unroll
  for (int m = 0; m < 4; ++m)
#pragma unroll
    for (int n = 0; n < NF; ++n) acc[m][n] = {0.f, 0.f, 0.f, 0.f};

  // stage R-row x 32-col bf16 tile: linear LDS dest (unit u -> u*16B,
  // wave-uniform base + lane*16), source pre-swizzled.
  auto stage = [&](const ushort* __restrict__ G, ushort* Lt, int base_row,
                   int k0, int nu /* = R*4 units */) {
    for (int u0 = 0; u0 < nu; u0 += 256) {
      const int u = u0 + t;
      const int row = u >> 2;
      const int sp = u & 3;
      const int sg = sp ^ ((row >> 1) & 3);
      gload_lds16(&G[(size_t)(base_row + row) * K + k0 + sg * 8], &Lt[u * 8]);
    }
  };

  for (int k0 = 0; k0 < K; k0 += GBK) {
    stage(Ah, sAh, bm, k0, 512);
    stage(Al, sAl, bm, k0, 512);
    stage(Bh, sBh, bn, k0, BN * 4);
    stage(Bl, sBl, bn, k0, BN * 4);
    __syncthreads();   // drains vmcnt before any LDS read

    short8 afh[4], afl[4], bfh[NF], bfl[NF];
#pragma unroll
    for (int m = 0; m < 4; ++m) {
      const int arow = wr * 64 + m * 16 + r16;
      const int off = arow * 64 + (((g ^ ((arow >> 1) & 3))) << 4);
      afh[m] = *reinterpret_cast<const short8*>((const char*)sAh + off);
      afl[m] = *reinterpret_cast<const short8*>((const char*)sAl + off);
    }
#pragma unroll
    for (int n = 0; n < NF; ++n) {
      const int brow = wc * (NF * 16) + n * 16 + r16;
      const int off = brow * 64 + (((g ^ ((brow >> 1) & 3))) << 4);
      bfh[n] = *reinterpret_cast<const short8*>((const char*)sBh + off);
      bfl[n] = *reinterpret_cast<const short8*>((const char*)sBl + off);
    }
#pragma unroll
    for (int m = 0; m < 4; ++m)
#pragma unroll
      for (int n = 0; n < NF; ++n) {
        acc[m][n] = __builtin_amdgcn_mfma_f32_16x16x32_bf16(
            afh[m], bfh[n], acc[m][n], 0, 0, 0);
        acc[m][n] = __builtin_amdgcn_mfma_f32_16x16x32_bf16(
            afh[m], bfl[n], acc[m][n], 0, 0, 0);
        acc[m][n] = __builtin_amdgcn_mfma_f32_16x16x32_bf16(
            afl[m], bfh[n], acc[m][n], 0, 0, 0);
      }
    __syncthreads();   // LDS reuse next iteration
  }

  // epilogue: C/D layout col = lane&15, row = (lane>>4)*4 + reg  (m89-verified)
#pragma unroll
  for (int n = 0; n < NF; ++n) {
    const int col = bn + wc * (NF * 16) + n * 16 + r16;
    const float bb = bias[col];
#pragma unroll
    for (int m = 0; m < 4; ++m) {
      const int row0 = bm + wr * 64 + m * 16 + g * 4;
#pragma unroll
      for (int j = 0; j < 4; ++j)
        C[(size_t)(row0 + j) * N + col] = acc[m][n][j] + bb;
    }
  }
}

// ---------------------------------------------------------------------------
// Depthwise causal conv (K=4) + conv bias + SiLU; then elu+1 for q/k channels.
// ---------------------------------------------------------------------------
__global__ __launch_bounds__(256) void conv_silu_act(
    const float* __restrict__ qkv, const float* __restrict__ conv_w,
    const float* __restrict__ conv_b, float* __restrict__ act) {
  const int gid = blockIdx.x * 256 + threadIdx.x;
  const int nc4 = C_CONV / 4;
  if (gid >= S_LEN * nc4) return;
  const int s = gid / nc4;
  const int c = (gid % nc4) * 4;

  float w[4][4];
#pragma unroll
  for (int cc = 0; cc < 4; ++cc) {
    const float4 wv = *reinterpret_cast<const float4*>(&conv_w[(c + cc) * 4]);
    w[cc][0] = wv.x; w[cc][1] = wv.y; w[cc][2] = wv.z; w[cc][3] = wv.w;
  }
  const float4 bv = *reinterpret_cast<const float4*>(&conv_b[c]);
  float z[4] = {bv.x, bv.y, bv.z, bv.w};

#pragma unroll
  for (int j = 0; j < 4; ++j) {
    const int sp = s - 3 + j;
    if (sp >= 0) {
      const float4 in = *reinterpret_cast<const float4*>(
          &qkv[(size_t)sp * C_CONV + c]);
      z[0] += in.x * w[0][j]; z[1] += in.y * w[1][j];
      z[2] += in.z * w[2][j]; z[3] += in.w * w[3][j];
    }
  }

  float out[4];
  const bool is_qk = (c < 2 * D_MODEL);
#pragma unroll
  for (int cc = 0; cc < 4; ++cc) {
    float a = z[cc] / (1.0f + expf(-z[cc]));           // silu
    if (is_qk) a = (a > 0.0f) ? (a + 1.0f) : expf(a);  // elu(a)+1
    out[cc] = a;
  }
  float4 ov = {out[0], out[1], out[2], out[3]};
  *reinterpret_cast<float4*>(&act[(size_t)s * C_CONV + c]) = ov;
}

// ---------------------------------------------------------------------------
// Pass 1: per-chunk KV outer-product sums and K sums. (register-tiled)
// ---------------------------------------------------------------------------
__global__ __launch_bounds__(256) void chunk_sums(
    const float* __restrict__ act, float* __restrict__ SC) {
  const int ch = blockIdx.x;
  const int h = blockIdx.y;
  const int t = threadIdx.x;
  __shared__ float ks[CHUNK][32];
  __shared__ float vs[CHUNK][36];   // padded for conflict-free float4 reads

#pragma unroll
  for (int i = 0; i < 2; ++i) {
    int idx = t + 256 * i;
    int r = idx >> 3;
    int c0 = (idx & 7) * 4;
    const size_t row = (size_t)(ch * CHUNK + r) * C_CONV;
    const float4 kv4 = *reinterpret_cast<const float4*>(
        &act[row + D_MODEL + h * 32 + c0]);
    *reinterpret_cast<float4*>(&ks[r][c0]) = kv4;
    const float4 vv4 = *reinterpret_cast<const float4*>(
        &act[row + 2 * D_MODEL + h * 32 + c0]);
    *reinterpret_cast<float4*>(&vs[r][c0]) = vv4;
  }
  __syncthreads();

  const int d = t >> 3;             // 0..31
  const int c4 = (t & 7) * 4;       // 0,4,...,28
  float4 acc = {0.f, 0.f, 0.f, 0.f};
  float ksum = 0.f;
#pragma unroll 4
  for (int s = 0; s < CHUNK; ++s) {
    const float kv = ks[s][d];
    const float4 vv = *reinterpret_cast<const float4*>(&vs[s][c4]);
    acc.x += kv * vv.x; acc.y += kv * vv.y;
    acc.z += kv * vv.z; acc.w += kv * vv.w;
    ksum += kv;
  }
  float* out = &SC[(size_t)(ch * H_HEADS + h) * SC_STRIDE];
  *reinterpret_cast<float4*>(&out[d * 32 + c4]) = acc;
  if ((t & 7) == 0) out[1024 + d] = ksum;
}

// ---------------------------------------------------------------------------
// Pass 2: exclusive prefix over chunks. One (h,e) per thread, grid (5, H).
// Per-step loads coalesced across threads; single 64-step scan per thread.
// ---------------------------------------------------------------------------
__global__ __launch_bounds__(256) void chunk_prefix(
    const float* __restrict__ SC, float* __restrict__ SP) {
  const int h = blockIdx.y;
  const int e = blockIdx.x * 256 + threadIdx.x;
  if (e >= SC_STRIDE) return;
  float run = 0.f;
  for (int c = 0; c < NCH; ++c) {
    const size_t off = (size_t)(c * H_HEADS + h) * SC_STRIDE + e;
    SP[off] = run;
    run += SC[off];
  }
}

// ---------------------------------------------------------------------------
// Pass 3: intra-chunk causal attention + inter-chunk state. (register-tiled)
// Writes ctx directly as bf16 hi/lo splits (fused epilogue for GEMM2).
// ---------------------------------------------------------------------------
__global__ __launch_bounds__(256) void chunk_ctx(
    const float* __restrict__ act, const float* __restrict__ SP,
    ushort* __restrict__ ctx_h, ushort* __restrict__ ctx_l) {
  const int ch = blockIdx.x;
  const int h = blockIdx.y;
  const int t = threadIdx.x;

  __shared__ float qs[CHUNK][36];     // Q rows, float4-readable, 2-way banks
  __shared__ float ksT[32][68];       // K transposed: ksT[d][s']
  __shared__ float vs[CHUNK][36];     // V rows, float4-readable
  __shared__ float KVp[32][36];       // KVprev[d][t], float4-readable
  __shared__ float Amat[CHUNK][68];   // masked scores
  __shared__ float Kp[32];
  __shared__ float denomp[CHUNK][4];
  __shared__ float denom[CHUNK];

  // ---- staging: coalesced global float4 loads
#pragma unroll
  for (int i = 0; i < 2; ++i) {
    const int idx = t + 256 * i;      // 0..511
    const int r = idx >> 3;
    const int c0 = (idx & 7) * 4;
    const size_t row = (size_t)(ch * CHUNK + r) * C_CONV;
    float4 v4;
    v4 = *reinterpret_cast<const float4*>(&act[row + h * 32 + c0]);
    *reinterpret_cast<float4*>(&qs[r][c0]) = v4;
    v4 = *reinterpret_cast<const float4*>(&act[row + D_MODEL + h * 32 + c0]);
    ksT[c0 + 0][r] = v4.x; ksT[c0 + 1][r] = v4.y;
    ksT[c0 + 2][r] = v4.z; ksT[c0 + 3][r] = v4.w;
    v4 = *reinterpret_cast<const float4*>(&act[row + 2 * D_MODEL + h * 32 + c0]);
    *reinterpret_cast<float4*>(&vs[r][c0]) = v4;
  }
  const float* sp = &SP[(size_t)(ch * H_HEADS + h) * SC_STRIDE];
  {
    const float4 v4 = *reinterpret_cast<const float4*>(&sp[t * 4]);
    *reinterpret_cast<float4*>(&KVp[t >> 3][(t & 7) * 4]) = v4;
  }
  if (t < 32) Kp[t] = sp[1024 + t];
  __syncthreads();

  // ---- step1: Amat = tril(Q K^T), 4x4 register tile per thread
  {
    const int tm = t >> 4;            // row group 0..15
    const int tn = t & 15;            // col group 0..15
    float a1[4][4] = {{0.f}};
#pragma unroll
    for (int g = 0; g < 8; ++g) {
      const int d0 = g * 4;
      float4 qv[4], kq[4];
#pragma unroll
      for (int i = 0; i < 4; ++i)
        qv[i] = *reinterpret_cast<const float4*>(&qs[tm * 4 + i][d0]);
#pragma unroll
      for (int dd = 0; dd < 4; ++dd)
        kq[dd] = *reinterpret_cast<const float4*>(&ksT[d0 + dd][tn * 4]);
#pragma unroll
      for (int i = 0; i < 4; ++i)
#pragma unroll
        for (int dd = 0; dd < 4; ++dd) {
          const float qa = F4C(qv[i], dd);
          a1[i][0] += qa * kq[dd].x;
          a1[i][1] += qa * kq[dd].y;
          a1[i][2] += qa * kq[dd].z;
          a1[i][3] += qa * kq[dd].w;
        }
    }
#pragma unroll
    for (int i = 0; i < 4; ++i) {
      const int s = tm * 4 + i;
      float4 o;
      o.x = (tn * 4 + 0 <= s) ? a1[i][0] : 0.f;
      o.y = (tn * 4 + 1 <= s) ? a1[i][1] : 0.f;
      o.z = (tn * 4 + 2 <= s) ? a1[i][2] : 0.f;
      o.w = (tn * 4 + 3 <= s) ? a1[i][3] : 0.f;
      *reinterpret_cast<float4*>(&Amat[s][tn * 4]) = o;
    }
  }
  __syncthreads();

  // ---- step2: denom, split across the 4 waves
  {
    const int row = t & 63;
    const int qd = t >> 6;            // 0..3
    float part = 0.f;
#pragma unroll
    for (int j = 0; j < 16; ++j) part += Amat[row][qd * 16 + j];
    if (qd < 2) {
#pragma unroll
      for (int j = 0; j < 16; ++j)
        part += qs[row][qd * 16 + j] * Kp[qd * 16 + j];
    }
    denomp[row][qd] = part;
  }
  __syncthreads();
  if (t < CHUNK) {
    const float4 dp = *reinterpret_cast<const float4*>(&denomp[t][0]);
    denom[t] = dp.x + dp.y + dp.z + dp.w;
  }
  __syncthreads();

  // ---- step3: ctx = (A·V + Q·KVp)/denom, 2 rows x 4 cols per thread
  {
    const int r2 = t >> 3;            // 0..31 -> rows 2*r2, 2*r2+1
    const int c4 = (t & 7) * 4;       // col group
    float a3[2][4] = {{0.f}};
#pragma unroll
    for (int sg = 0; sg < 16; ++sg) {
      const int s0 = sg * 4;
      float4 av[2];
      av[0] = *reinterpret_cast<const float4*>(&Amat[r2 * 2 + 0][s0]);
      av[1] = *reinterpret_cast<const float4*>(&Amat[r2 * 2 + 1][s0]);
      float4 vv[4];
#pragma unroll
      for (int ss = 0; ss < 4; ++ss)
        vv[ss] = *reinterpret_cast<const float4*>(&vs[s0 + ss][c4]);
#pragma unroll
      for (int i = 0; i < 2; ++i)
#pragma unroll
        for (int ss = 0; ss < 4; ++ss) {
          const float aa = F4C(av[i], ss);
          a3[i][0] += aa * vv[ss].x;
          a3[i][1] += aa * vv[ss].y;
          a3[i][2] += aa * vv[ss].z;
          a3[i][3] += aa * vv[ss].w;
        }
    }
#pragma unroll
    for (int g = 0; g < 8; ++g) {
      const int d0 = g * 4;
      float4 qv[2];
      qv[0] = *reinterpret_cast<const float4*>(&qs[r2 * 2 + 0][d0]);
      qv[1] = *reinterpret_cast<const float4*>(&qs[r2 * 2 + 1][d0]);
      float4 kv[4];
#pragma unroll
      for (int dd = 0; dd < 4; ++dd)
        kv[dd] = *reinterpret_cast<const float4*>(&KVp[d0 + dd][c4]);
#pragma unroll
      for (int i = 0; i < 2; ++i)
#pragma unroll
        for (int dd = 0; dd < 4; ++dd) {
          const float qa = F4C(qv[i], dd);
          a3[i][0] += qa * kv[dd].x;
          a3[i][1] += qa * kv[dd].y;
          a3[i][2] += qa * kv[dd].z;
          a3[i][3] += qa * kv[dd].w;
        }
    }
    // epilogue: divide + fused bf16 hi/lo split, vectorized ushort4 stores
#pragma unroll
    for (int i = 0; i < 2; ++i) {
      const int srow = r2 * 2 + i;
      const float dn = denom[srow];
      const size_t off = (size_t)(ch * CHUNK + srow) * D_MODEL + h * 32 + c4;
      ushort4 hv, lv;
      ushort hh[4], ll[4];
#pragma unroll
      for (int c = 0; c < 4; ++c) {
        const float val = a3[i][c] / dn;
        const ushort hb = f32_to_bf16_rne(val);
        hh[c] = hb;
        ll[c] = f32_to_bf16_rne(val - __uint_as_float((unsigned)hb << 16));
      }
      hv.x = hh[0]; hv.y = hh[1]; hv.z = hh[2]; hv.w = hh[3];
      lv.x = ll[0]; lv.y = ll[1]; lv.z = ll[2]; lv.w = ll[3];
      *reinterpret_cast<ushort4*>(&ctx_h[off]) = hv;
      *reinterpret_cast<ushort4*>(&ctx_l[off]) = lv;
    }
  }
}

// ---------------------------------------------------------------------------
// Workspace layout (bytes), total 96 MB required (see round-4 comments).
// ---------------------------------------------------------------------------
extern "C" void kernel_launch(void* const* d_in, const int* in_sizes, int n_in,
                              void* d_out, int out_size, void* d_ws, size_t ws_size,
                              hipStream_t stream) {
  const float* x      = (const float*)d_in[0];
  const float* Wqkv_w = (const float*)d_in[1];
  const float* Wqkv_b = (const float*)d_in[2];
  const float* conv_w = (const float*)d_in[3];
  const float* conv_b = (const float*)d_in[4];
  const float* out_w  = (const float*)d_in[5];
  const float* out_b  = (const float*)d_in[6];
  float* out = (float*)d_out;

  char* ws = (char*)d_ws;
  float*  qkv_raw = (float*)(ws);
  float*  SC      = (float*)(ws);
  float*  SP      = (float*)(ws + 8650752);
  ushort* ch      = (ushort*)(ws + 17301504);
  ushort* cl      = (ushort*)(ws + 25690112);
  float*  act     = (float*)(ws + 50331648);
  ushort* xh      = (ushort*)(ws + 50331648);
  ushort* xl      = (ushort*)(ws + 58720256);
  ushort* wh      = (ushort*)(ws + 67108864);
  ushort* wl      = (ushort*)(ws + 73400320);
  ushort* oh      = (ushort*)(ws + 50331648);
  ushort* ol      = (ushort*)(ws + 52428800);

  // 0. split x and Wqkv_w into bf16 hi/lo (single fused launch, exact fit:
  //    (1048576 + 786432) / 256 = 7168 blocks)
  split_bf16_x2<<<7168, 256, 0, stream>>>(
      x, xh, xl, S_LEN * D_MODEL / 4,
      Wqkv_w, wh, wl, C_CONV * D_MODEL / 4);

  // 1. QKV GEMM (bf16-split3 MFMA, BK=32): -> qkv_raw [4096][3072]
  {
    dim3 grid(C_CONV / 128, S_LEN / GBM);   // 24 x 32 = 768 blocks
    gemm_nt_split3<4><<<grid, 256, 0, stream>>>(xh, xl, wh, wl, Wqkv_b,
                                                qkv_raw, S_LEN, C_CONV,
                                                D_MODEL);
  }
  // 2. causal depthwise conv + SiLU + elu+1 -> act (overwrites xh..wl region)
  {
    int total = S_LEN * (C_CONV / 4);
    conv_silu_act<<<(total + 255) / 256, 256, 0, stream>>>(qkv_raw, conv_w,
                                                           conv_b, act);
  }
  // 3. chunk KV sums (overwrites qkv_raw region)
  {
    dim3 grid(NCH, H_HEADS);
    chunk_sums<<<grid, 256, 0, stream>>>(act, SC);
  }
  // 4. exclusive prefix over chunks (one e per thread, 160 blocks)
  {
    dim3 grid((SC_STRIDE + 255) / 256, H_HEADS);
    chunk_prefix<<<grid, 256, 0, stream>>>(SC, SP);
  }
  // 5. intra-chunk attention -> ctx bf16 hi/lo (fused split)
  {
    dim3 grid(NCH, H_HEADS);
    chunk_ctx<<<grid, 256, 0, stream>>>(act, SP, ch, cl);
  }
  // 6. split out_w (act now dead), then output GEMM (NF=4: BN=128, 256 blocks)
  split_bf16<<<1024, 256, 0, stream>>>(out_w, oh, ol, D_MODEL * D_MODEL / 4);
  {
    dim3 grid(D_MODEL / 128, S_LEN / GBM);  // 8 x 32 = 256 blocks
    gemm_nt_split3<4><<<grid, 256, 0, stream>>>(ch, cl, oh, ol, out_b, out,
                                                S_LEN, D_MODEL, D_MODEL);
  }
}

// Round 13
// 302.768 us; speedup vs baseline: 1.0765x; 1.0614x over previous
//
#include <hip/hip_runtime.h>
#include <hip/hip_bf16.h>
#include <math.h>

// Problem constants
#define S_LEN 4096
#define D_MODEL 1024
#define C_CONV 3072
#define H_HEADS 32
#define HEAD_D 32
#define V_D 32
#define K_CONV 4
#define CHUNK 64
#define NCH (S_LEN / CHUNK)                 // 64
#define SC_STRIDE (HEAD_D * V_D + HEAD_D)   // 1056 floats per (chunk, head)

typedef __attribute__((ext_vector_type(8))) short short8;
typedef __attribute__((ext_vector_type(4))) float f32x4;

// compile-time float4 component access (folds under #pragma unroll)
#define F4C(v, k) ((k) == 0 ? (v).x : (k) == 1 ? (v).y : (k) == 2 ? (v).z : (v).w)

// ---------------------------------------------------------------------------
// helpers
// ---------------------------------------------------------------------------
__device__ __forceinline__ ushort f32_to_bf16_rne(float f) {
  unsigned u = __float_as_uint(f);
  unsigned rounding = 0x7FFFu + ((u >> 16) & 1u);
  return (ushort)((u + rounding) >> 16);
}

__device__ __forceinline__ void gload_lds16(const void* g, void* l) {
  __builtin_amdgcn_global_load_lds(
      (const __attribute__((address_space(1))) void*)g,
      (__attribute__((address_space(3))) void*)l, 16, 0, 0);
}

__device__ __forceinline__ void split_one4(const float* __restrict__ in,
                                           ushort* __restrict__ hi,
                                           ushort* __restrict__ lo, int i) {
  const float4 v = reinterpret_cast<const float4*>(in)[i];
  float arr[4] = {v.x, v.y, v.z, v.w};
  ushort hh[4], ll[4];
#pragma unroll
  for (int j = 0; j < 4; ++j) {
    const ushort hb = f32_to_bf16_rne(arr[j]);
    const float hf = __uint_as_float((unsigned)hb << 16);
    hh[j] = hb;
    ll[j] = f32_to_bf16_rne(arr[j] - hf);
  }
  ushort4 h = {hh[0], hh[1], hh[2], hh[3]};
  ushort4 lw = {ll[0], ll[1], ll[2], ll[3]};
  reinterpret_cast<ushort4*>(hi)[i] = h;
  reinterpret_cast<ushort4*>(lo)[i] = lw;
}

// fp32 -> (bf16 hi, bf16 lo) split, single tensor (grid-stride).
__global__ __launch_bounds__(256) void split_bf16(
    const float* __restrict__ in, ushort* __restrict__ hi,
    ushort* __restrict__ lo, int n4) {
  int i = blockIdx.x * 256 + threadIdx.x;
  const int stride = gridDim.x * 256;
  for (; i < n4; i += stride) split_one4(in, hi, lo, i);
}

// fused split of TWO tensors in one launch (grid covers n4a+n4b exactly).
__global__ __launch_bounds__(256) void split_bf16_x2(
    const float* __restrict__ a, ushort* __restrict__ ah,
    ushort* __restrict__ al, int n4a,
    const float* __restrict__ b, ushort* __restrict__ bh,
    ushort* __restrict__ bl, int n4b) {
  const int gid = blockIdx.x * 256 + threadIdx.x;
  if (gid < n4a) {
    split_one4(a, ah, al, gid);
  } else if (gid < n4a + n4b) {
    split_one4(b, bh, bl, gid - n4a);
  }
}

// ---------------------------------------------------------------------------
// bf16-split-3 NT GEMM, BK=32, 2-PHASE double-buffered pipeline (T3 minimum):
//   prologue: STAGE(buf0); barrier;
//   iter t:   STAGE(buf^1, t+1) [loads in flight] ; ds_read buf ; MFMA ;
//             one __syncthreads (drains vmcnt+lgkm) ; swap.
// One barrier per K-step (was 2); staging latency hides under 192 MFMAs.
// LDS 2 x 32KB. Swizzle per rule 21 (involution both sides).
// ---------------------------------------------------------------------------
#define GBM 128
#define GBK 32

template <int NF>   // B-fragments per wave; BN = NF*32
__global__ __launch_bounds__(256, 4) void gemm_nt_split3(
    const ushort* __restrict__ Ah, const ushort* __restrict__ Al,
    const ushort* __restrict__ Bh, const ushort* __restrict__ Bl,
    const float* __restrict__ bias, float* __restrict__ C,
    int M, int N, int K) {
  constexpr int BN = NF * 32;
  constexpr int BUF = 8192 + 2 * BN * 32;   // ushorts per buffer
  __shared__ ushort lds[2][BUF];

  const int t = threadIdx.x;
  const int l = t & 63;
  const int w = t >> 6;          // wave 0..3
  const int wr = w >> 1;         // wave row (0..1)
  const int wc = w & 1;          // wave col (0..1)
  const int bm = blockIdx.y * GBM;
  const int bn = blockIdx.x * BN;
  const int r16 = l & 15;
  const int g = l >> 4;          // k-slot 0..3 (k = g*8)

  f32x4 acc[4][NF];
#pragma unroll
  for (int m = 0; m < 4; ++m)
#pragma unroll
    for (int n = 0; n < NF; ++n) acc[m][n] = {0.f, 0.f, 0.f, 0.f};

  // stage R-row x 32-col bf16 tile: linear LDS dest (unit u -> u*16B,
  // wave-uniform base + lane*16), source pre-swizzled.
  auto stage = [&](const ushort* __restrict__ G, ushort* Lt, int base_row,
                   int k0, int nu) {
    for (int u0 = 0; u0 < nu; u0 += 256) {
      const int u = u0 + t;
      const int row = u >> 2;
      const int sp = u & 3;
      const int sg = sp ^ ((row >> 1) & 3);
      gload_lds16(&G[(size_t)(base_row + row) * K + k0 + sg * 8], &Lt[u * 8]);
    }
  };
  auto stageAll = [&](int buf, int k0) {
    stage(Ah, &lds[buf][0], bm, k0, 512);
    stage(Al, &lds[buf][4096], bm, k0, 512);
    stage(Bh, &lds[buf][8192], bn, k0, BN * 4);
    stage(Bl, &lds[buf][8192 + BN * 32], bn, k0, BN * 4);
  };

  const int nsteps = K / GBK;
  stageAll(0, 0);
  __syncthreads();   // vmcnt(0) drain + barrier: buf0 ready

  int cur = 0;
  for (int ts = 0; ts < nsteps; ++ts) {
    if (ts + 1 < nsteps) stageAll(cur ^ 1, (ts + 1) * GBK);  // prefetch

    const ushort* sAh = &lds[cur][0];
    const ushort* sAl = &lds[cur][4096];
    const ushort* sBh = &lds[cur][8192];
    const ushort* sBl = &lds[cur][8192 + BN * 32];

    short8 afh[4], afl[4], bfh[NF], bfl[NF];
#pragma unroll
    for (int m = 0; m < 4; ++m) {
      const int arow = wr * 64 + m * 16 + r16;
      const int off = arow * 64 + (((g ^ ((arow >> 1) & 3))) << 4);
      afh[m] = *reinterpret_cast<const short8*>((const char*)sAh + off);
      afl[m] = *reinterpret_cast<const short8*>((const char*)sAl + off);
    }
#pragma unroll
    for (int n = 0; n < NF; ++n) {
      const int brow = wc * (NF * 16) + n * 16 + r16;
      const int off = brow * 64 + (((g ^ ((brow >> 1) & 3))) << 4);
      bfh[n] = *reinterpret_cast<const short8*>((const char*)sBh + off);
      bfl[n] = *reinterpret_cast<const short8*>((const char*)sBl + off);
    }
#pragma unroll
    for (int m = 0; m < 4; ++m)
#pragma unroll
      for (int n = 0; n < NF; ++n) {
        acc[m][n] = __builtin_amdgcn_mfma_f32_16x16x32_bf16(
            afh[m], bfh[n], acc[m][n], 0, 0, 0);
        acc[m][n] = __builtin_amdgcn_mfma_f32_16x16x32_bf16(
            afh[m], bfl[n], acc[m][n], 0, 0, 0);
        acc[m][n] = __builtin_amdgcn_mfma_f32_16x16x32_bf16(
            afl[m], bfh[n], acc[m][n], 0, 0, 0);
      }
    __syncthreads();   // drains prefetch (vmcnt) + reads (lgkm); swap safe
    cur ^= 1;
  }

  // epilogue: C/D layout col = lane&15, row = (lane>>4)*4 + reg  (m89-verified)
#pragma unroll
  for (int n = 0; n < NF; ++n) {
    const int col = bn + wc * (NF * 16) + n * 16 + r16;
    const float bb = bias[col];
#pragma unroll
    for (int m = 0; m < 4; ++m) {
      const int row0 = bm + wr * 64 + m * 16 + g * 4;
#pragma unroll
      for (int j = 0; j < 4; ++j)
        C[(size_t)(row0 + j) * N + col] = acc[m][n][j] + bb;
    }
  }
}

// ---------------------------------------------------------------------------
// Depthwise causal conv (K=4) + conv bias + SiLU; then elu+1 for q/k channels.
// ---------------------------------------------------------------------------
__global__ __launch_bounds__(256) void conv_silu_act(
    const float* __restrict__ qkv, const float* __restrict__ conv_w,
    const float* __restrict__ conv_b, float* __restrict__ act) {
  const int gid = blockIdx.x * 256 + threadIdx.x;
  const int nc4 = C_CONV / 4;
  if (gid >= S_LEN * nc4) return;
  const int s = gid / nc4;
  const int c = (gid % nc4) * 4;

  float w[4][4];
#pragma unroll
  for (int cc = 0; cc < 4; ++cc) {
    const float4 wv = *reinterpret_cast<const float4*>(&conv_w[(c + cc) * 4]);
    w[cc][0] = wv.x; w[cc][1] = wv.y; w[cc][2] = wv.z; w[cc][3] = wv.w;
  }
  const float4 bv = *reinterpret_cast<const float4*>(&conv_b[c]);
  float z[4] = {bv.x, bv.y, bv.z, bv.w};

#pragma unroll
  for (int j = 0; j < 4; ++j) {
    const int sp = s - 3 + j;
    if (sp >= 0) {
      const float4 in = *reinterpret_cast<const float4*>(
          &qkv[(size_t)sp * C_CONV + c]);
      z[0] += in.x * w[0][j]; z[1] += in.y * w[1][j];
      z[2] += in.z * w[2][j]; z[3] += in.w * w[3][j];
    }
  }

  float out[4];
  const bool is_qk = (c < 2 * D_MODEL);
#pragma unroll
  for (int cc = 0; cc < 4; ++cc) {
    float a = z[cc] / (1.0f + expf(-z[cc]));           // silu
    if (is_qk) a = (a > 0.0f) ? (a + 1.0f) : expf(a);  // elu(a)+1
    out[cc] = a;
  }
  float4 ov = {out[0], out[1], out[2], out[3]};
  *reinterpret_cast<float4*>(&act[(size_t)s * C_CONV + c]) = ov;
}

// ---------------------------------------------------------------------------
// Pass 1: per-chunk KV outer-product sums and K sums. (register-tiled)
// ---------------------------------------------------------------------------
__global__ __launch_bounds__(256) void chunk_sums(
    const float* __restrict__ act, float* __restrict__ SC) {
  const int ch = blockIdx.x;
  const int h = blockIdx.y;
  const int t = threadIdx.x;
  __shared__ float ks[CHUNK][32];
  __shared__ float vs[CHUNK][36];   // padded for conflict-free float4 reads

#pragma unroll
  for (int i = 0; i < 2; ++i) {
    int idx = t + 256 * i;
    int r = idx >> 3;
    int c0 = (idx & 7) * 4;
    const size_t row = (size_t)(ch * CHUNK + r) * C_CONV;
    const float4 kv4 = *reinterpret_cast<const float4*>(
        &act[row + D_MODEL + h * 32 + c0]);
    *reinterpret_cast<float4*>(&ks[r][c0]) = kv4;
    const float4 vv4 = *reinterpret_cast<const float4*>(
        &act[row + 2 * D_MODEL + h * 32 + c0]);
    *reinterpret_cast<float4*>(&vs[r][c0]) = vv4;
  }
  __syncthreads();

  const int d = t >> 3;             // 0..31
  const int c4 = (t & 7) * 4;       // 0,4,...,28
  float4 acc = {0.f, 0.f, 0.f, 0.f};
  float ksum = 0.f;
#pragma unroll 4
  for (int s = 0; s < CHUNK; ++s) {
    const float kv = ks[s][d];
    const float4 vv = *reinterpret_cast<const float4*>(&vs[s][c4]);
    acc.x += kv * vv.x; acc.y += kv * vv.y;
    acc.z += kv * vv.z; acc.w += kv * vv.w;
    ksum += kv;
  }
  float* out = &SC[(size_t)(ch * H_HEADS + h) * SC_STRIDE];
  *reinterpret_cast<float4*>(&out[d * 32 + c4]) = acc;
  if ((t & 7) == 0) out[1024 + d] = ksum;
}

// ---------------------------------------------------------------------------
// Pass 2: exclusive prefix over chunks. One (h,e) per thread, grid (5, H).
// ---------------------------------------------------------------------------
__global__ __launch_bounds__(256) void chunk_prefix(
    const float* __restrict__ SC, float* __restrict__ SP) {
  const int h = blockIdx.y;
  const int e = blockIdx.x * 256 + threadIdx.x;
  if (e >= SC_STRIDE) return;
  float run = 0.f;
  for (int c = 0; c < NCH; ++c) {
    const size_t off = (size_t)(c * H_HEADS + h) * SC_STRIDE + e;
    SP[off] = run;
    run += SC[off];
  }
}

// ---------------------------------------------------------------------------
// Pass 3: intra-chunk causal attention + inter-chunk state. (register-tiled)
// Writes ctx directly as bf16 hi/lo splits (fused epilogue for GEMM2).
// ---------------------------------------------------------------------------
__global__ __launch_bounds__(256) void chunk_ctx(
    const float* __restrict__ act, const float* __restrict__ SP,
    ushort* __restrict__ ctx_h, ushort* __restrict__ ctx_l) {
  const int ch = blockIdx.x;
  const int h = blockIdx.y;
  const int t = threadIdx.x;

  __shared__ float qs[CHUNK][36];     // Q rows, float4-readable, 2-way banks
  __shared__ float ksT[32][68];       // K transposed: ksT[d][s']
  __shared__ float vs[CHUNK][36];     // V rows, float4-readable
  __shared__ float KVp[32][36];       // KVprev[d][t], float4-readable
  __shared__ float Amat[CHUNK][68];   // masked scores
  __shared__ float Kp[32];
  __shared__ float denomp[CHUNK][4];
  __shared__ float denom[CHUNK];

  // ---- staging: coalesced global float4 loads
#pragma unroll
  for (int i = 0; i < 2; ++i) {
    const int idx = t + 256 * i;      // 0..511
    const int r = idx >> 3;
    const int c0 = (idx & 7) * 4;
    const size_t row = (size_t)(ch * CHUNK + r) * C_CONV;
    float4 v4;
    v4 = *reinterpret_cast<const float4*>(&act[row + h * 32 + c0]);
    *reinterpret_cast<float4*>(&qs[r][c0]) = v4;
    v4 = *reinterpret_cast<const float4*>(&act[row + D_MODEL + h * 32 + c0]);
    ksT[c0 + 0][r] = v4.x; ksT[c0 + 1][r] = v4.y;
    ksT[c0 + 2][r] = v4.z; ksT[c0 + 3][r] = v4.w;
    v4 = *reinterpret_cast<const float4*>(&act[row + 2 * D_MODEL + h * 32 + c0]);
    *reinterpret_cast<float4*>(&vs[r][c0]) = v4;
  }
  const float* sp = &SP[(size_t)(ch * H_HEADS + h) * SC_STRIDE];
  {
    const float4 v4 = *reinterpret_cast<const float4*>(&sp[t * 4]);
    *reinterpret_cast<float4*>(&KVp[t >> 3][(t & 7) * 4]) = v4;
  }
  if (t < 32) Kp[t] = sp[1024 + t];
  __syncthreads();

  // ---- step1: Amat = tril(Q K^T), 4x4 register tile per thread
  {
    const int tm = t >> 4;            // row group 0..15
    const int tn = t & 15;            // col group 0..15
    float a1[4][4] = {{0.f}};
#pragma unroll
    for (int g = 0; g < 8; ++g) {
      const int d0 = g * 4;
      float4 qv[4], kq[4];
#pragma unroll
      for (int i = 0; i < 4; ++i)
        qv[i] = *reinterpret_cast<const float4*>(&qs[tm * 4 + i][d0]);
#pragma unroll
      for (int dd = 0; dd < 4; ++dd)
        kq[dd] = *reinterpret_cast<const float4*>(&ksT[d0 + dd][tn * 4]);
#pragma unroll
      for (int i = 0; i < 4; ++i)
#pragma unroll
        for (int dd = 0; dd < 4; ++dd) {
          const float qa = F4C(qv[i], dd);
          a1[i][0] += qa * kq[dd].x;
          a1[i][1] += qa * kq[dd].y;
          a1[i][2] += qa * kq[dd].z;
          a1[i][3] += qa * kq[dd].w;
        }
    }
#pragma unroll
    for (int i = 0; i < 4; ++i) {
      const int s = tm * 4 + i;
      float4 o;
      o.x = (tn * 4 + 0 <= s) ? a1[i][0] : 0.f;
      o.y = (tn * 4 + 1 <= s) ? a1[i][1] : 0.f;
      o.z = (tn * 4 + 2 <= s) ? a1[i][2] : 0.f;
      o.w = (tn * 4 + 3 <= s) ? a1[i][3] : 0.f;
      *reinterpret_cast<float4*>(&Amat[s][tn * 4]) = o;
    }
  }
  __syncthreads();

  // ---- step2: denom, split across the 4 waves
  {
    const int row = t & 63;
    const int qd = t >> 6;            // 0..3
    float part = 0.f;
#pragma unroll
    for (int j = 0; j < 16; ++j) part += Amat[row][qd * 16 + j];
    if (qd < 2) {
#pragma unroll
      for (int j = 0; j < 16; ++j)
        part += qs[row][qd * 16 + j] * Kp[qd * 16 + j];
    }
    denomp[row][qd] = part;
  }
  __syncthreads();
  if (t < CHUNK) {
    const float4 dp = *reinterpret_cast<const float4*>(&denomp[t][0]);
    denom[t] = dp.x + dp.y + dp.z + dp.w;
  }
  __syncthreads();

  // ---- step3: ctx = (A·V + Q·KVp)/denom, 2 rows x 4 cols per thread
  {
    const int r2 = t >> 3;            // 0..31 -> rows 2*r2, 2*r2+1
    const int c4 = (t & 7) * 4;       // col group
    float a3[2][4] = {{0.f}};
#pragma unroll
    for (int sg = 0; sg < 16; ++sg) {
      const int s0 = sg * 4;
      float4 av[2];
      av[0] = *reinterpret_cast<const float4*>(&Amat[r2 * 2 + 0][s0]);
      av[1] = *reinterpret_cast<const float4*>(&Amat[r2 * 2 + 1][s0]);
      float4 vv[4];
#pragma unroll
      for (int ss = 0; ss < 4; ++ss)
        vv[ss] = *reinterpret_cast<const float4*>(&vs[s0 + ss][c4]);
#pragma unroll
      for (int i = 0; i < 2; ++i)
#pragma unroll
        for (int ss = 0; ss < 4; ++ss) {
          const float aa = F4C(av[i], ss);
          a3[i][0] += aa * vv[ss].x;
          a3[i][1] += aa * vv[ss].y;
          a3[i][2] += aa * vv[ss].z;
          a3[i][3] += aa * vv[ss].w;
        }
    }
#pragma unroll
    for (int g = 0; g < 8; ++g) {
      const int d0 = g * 4;
      float4 qv[2];
      qv[0] = *reinterpret_cast<const float4*>(&qs[r2 * 2 + 0][d0]);
      qv[1] = *reinterpret_cast<const float4*>(&qs[r2 * 2 + 1][d0]);
      float4 kv[4];
#pragma unroll
      for (int dd = 0; dd < 4; ++dd)
        kv[dd] = *reinterpret_cast<const float4*>(&KVp[d0 + dd][c4]);
#pragma unroll
      for (int i = 0; i < 2; ++i)
#pragma unroll
        for (int dd = 0; dd < 4; ++dd) {
          const float qa = F4C(qv[i], dd);
          a3[i][0] += qa * kv[dd].x;
          a3[i][1] += qa * kv[dd].y;
          a3[i][2] += qa * kv[dd].z;
          a3[i][3] += qa * kv[dd].w;
        }
    }
    // epilogue: divide + fused bf16 hi/lo split, vectorized ushort4 stores
#pragma unroll
    for (int i = 0; i < 2; ++i) {
      const int srow = r2 * 2 + i;
      const float dn = denom[srow];
      const size_t off = (size_t)(ch * CHUNK + srow) * D_MODEL + h * 32 + c4;
      ushort4 hv, lv;
      ushort hh[4], ll[4];
#pragma unroll
      for (int c = 0; c < 4; ++c) {
        const float val = a3[i][c] / dn;
        const ushort hb = f32_to_bf16_rne(val);
        hh[c] = hb;
        ll[c] = f32_to_bf16_rne(val - __uint_as_float((unsigned)hb << 16));
      }
      hv.x = hh[0]; hv.y = hh[1]; hv.z = hh[2]; hv.w = hh[3];
      lv.x = ll[0]; lv.y = ll[1]; lv.z = ll[2]; lv.w = ll[3];
      *reinterpret_cast<ushort4*>(&ctx_h[off]) = hv;
      *reinterpret_cast<ushort4*>(&ctx_l[off]) = lv;
    }
  }
}

// ---------------------------------------------------------------------------
// Workspace layout (bytes), total 96 MB required (see round-4 comments).
// ---------------------------------------------------------------------------
extern "C" void kernel_launch(void* const* d_in, const int* in_sizes, int n_in,
                              void* d_out, int out_size, void* d_ws, size_t ws_size,
                              hipStream_t stream) {
  const float* x      = (const float*)d_in[0];
  const float* Wqkv_w = (const float*)d_in[1];
  const float* Wqkv_b = (const float*)d_in[2];
  const float* conv_w = (const float*)d_in[3];
  const float* conv_b = (const float*)d_in[4];
  const float* out_w  = (const float*)d_in[5];
  const float* out_b  = (const float*)d_in[6];
  float* out = (float*)d_out;

  char* ws = (char*)d_ws;
  float*  qkv_raw = (float*)(ws);
  float*  SC      = (float*)(ws);
  float*  SP      = (float*)(ws + 8650752);
  ushort* ch      = (ushort*)(ws + 17301504);
  ushort* cl      = (ushort*)(ws + 25690112);
  float*  act     = (float*)(ws + 50331648);
  ushort* xh      = (ushort*)(ws + 50331648);
  ushort* xl      = (ushort*)(ws + 58720256);
  ushort* wh      = (ushort*)(ws + 67108864);
  ushort* wl      = (ushort*)(ws + 73400320);
  ushort* oh      = (ushort*)(ws + 50331648);
  ushort* ol      = (ushort*)(ws + 52428800);

  // 0. split x and Wqkv_w into bf16 hi/lo (single fused launch)
  split_bf16_x2<<<7168, 256, 0, stream>>>(
      x, xh, xl, S_LEN * D_MODEL / 4,
      Wqkv_w, wh, wl, C_CONV * D_MODEL / 4);

  // 1. QKV GEMM (bf16-split3 MFMA, BK=32, 2-phase dbuf): -> qkv_raw
  {
    dim3 grid(C_CONV / 128, S_LEN / GBM);   // 24 x 32 = 768 blocks
    gemm_nt_split3<4><<<grid, 256, 0, stream>>>(xh, xl, wh, wl, Wqkv_b,
                                                qkv_raw, S_LEN, C_CONV,
                                                D_MODEL);
  }
  // 2. causal depthwise conv + SiLU + elu+1 -> act (overwrites xh..wl region)
  {
    int total = S_LEN * (C_CONV / 4);
    conv_silu_act<<<(total + 255) / 256, 256, 0, stream>>>(qkv_raw, conv_w,
                                                           conv_b, act);
  }
  // 3. chunk KV sums (overwrites qkv_raw region)
  {
    dim3 grid(NCH, H_HEADS);
    chunk_sums<<<grid, 256, 0, stream>>>(act, SC);
  }
  // 4. exclusive prefix over chunks (one e per thread, 160 blocks)
  {
    dim3 grid((SC_STRIDE + 255) / 256, H_HEADS);
    chunk_prefix<<<grid, 256, 0, stream>>>(SC, SP);
  }
  // 5. intra-chunk attention -> ctx bf16 hi/lo (fused split)
  {
    dim3 grid(NCH, H_HEADS);
    chunk_ctx<<<grid, 256, 0, stream>>>(act, SP, ch, cl);
  }
  // 6. split out_w (act now dead), then output GEMM (NF=4: BN=128, 256 blocks)
  split_bf16<<<1024, 256, 0, stream>>>(out_w, oh, ol, D_MODEL * D_MODEL / 4);
  {
    dim3 grid(D_MODEL / 128, S_LEN / GBM);  // 8 x 32 = 256 blocks
    gemm_nt_split3<4><<<grid, 256, 0, stream>>>(ch, cl, oh, ol, out_b, out,
                                                S_LEN, D_MODEL, D_MODEL);
  }
}